// Round 16
// baseline (318.417 us; speedup 1.0000x reference)
//
#include <hip/hip_runtime.h>

// GCN 4-layer forward on MI355X.
// Reference: h' = relu( norm_dst * segsum_{dst}( ((h*norm_src) @ W)[src] ) + b )
//
// Round 16: unfuse the atomic drain. r15 post-mortem: deg+gemm0 fusion never
// paid (79us ≈ 60 standalone drain + 14 gemm + interference; r15's 10-deep
// burst made it 99). Now: deg_loc standalone at full parallelism (2344 blks,
// r7-measured 60us), and gemm0 rides WITH scatter instead (random-write
// latency-bound + VALU-bound = complementary; both legal pre-gather0).

namespace {

constexpr int NN = 50000;      // nodes
constexpr int NE = 600000;     // edges
constexpr int SCAN_BLK = 256;
constexpr int NBLK = (NN + SCAN_BLK - 1) / SCAN_BLK;  // 196
constexpr int EB = (NE + 255) / 256;                  // 2344 edge blocks
constexpr int GEMM_TILES = (NN + 63) / 64;            // 782

typedef unsigned short bhalf;

__device__ inline float blo(unsigned int v) {  // low bf16 of a packed word
  return __uint_as_float(v << 16);
}
__device__ inline float bhi(unsigned int v) {  // high bf16 of a packed word
  return __uint_as_float(v & 0xFFFF0000u);
}
__device__ inline unsigned int f2b_bits(float f) {  // RNE bf16 in high 16 bits
  unsigned int b = __float_as_uint(f);
  return b + 0x7FFFu + ((b >> 16) & 1u);
}
__device__ inline unsigned int pack2(float lo, float hi) {
  return (f2b_bits(lo) >> 16) | (f2b_bits(hi) & 0xFFFF0000u);
}

// degree counting + le slots, full-grid single-edge-per-thread (r7: ~60us)
__global__ void deg_loc_kernel(const int* __restrict__ src, const int* __restrict__ dst,
                               int* __restrict__ dego, int* __restrict__ degi,
                               int* __restrict__ le) {
  int e = blockIdx.x * blockDim.x + threadIdx.x;
  if (e < NE) {
    atomicAdd(&dego[src[e]], 1);
    le[e] = atomicAdd(&degi[dst[e]], 1);
  }
}

// --- scan phase 1 + norms: per-block sum of degi -> bsum; ns/nd from degs ---
__global__ __launch_bounds__(SCAN_BLK) void scan1_norm(const int* __restrict__ dego,
                                                       const int* __restrict__ degi,
                                                       int* __restrict__ bsum,
                                                       float* __restrict__ ns,
                                                       float* __restrict__ nd) {
  __shared__ int ws[SCAN_BLK / 64];
  int i = blockIdx.x * SCAN_BLK + threadIdx.x;
  int v = 0;
  if (i < NN) {
    int din = degi[i];
    int dout = dego[i];
    v = din;
    int a = dout < 1 ? 1 : dout;
    int b = din < 1 ? 1 : din;
    ns[i] = 1.0f / sqrtf((float)a);
    nd[i] = 1.0f / sqrtf((float)b);
  }
#pragma unroll
  for (int off = 32; off; off >>= 1) v += __shfl_down(v, off, 64);
  int lane = threadIdx.x & 63, w = threadIdx.x >> 6;
  if (lane == 0) ws[w] = v;
  __syncthreads();
  if (threadIdx.x == 0) {
    int s = 0;
#pragma unroll
    for (int k = 0; k < SCAN_BLK / 64; ++k) s += ws[k];
    bsum[blockIdx.x] = s;
  }
}

__global__ __launch_bounds__(256) void scan_phase2(const int* __restrict__ bsum,
                                                   int* __restrict__ bpre,
                                                   int* __restrict__ rowptr) {
  __shared__ int s[256];
  int t = threadIdx.x;
  int v = (t < NBLK) ? bsum[t] : 0;
  s[t] = v;
  __syncthreads();
  for (int off = 1; off < 256; off <<= 1) {
    int u = (t >= off) ? s[t - off] : 0;
    __syncthreads();
    s[t] += u;
    __syncthreads();
  }
  if (t < NBLK) bpre[t] = s[t] - v;  // exclusive
  if (t == 255) rowptr[NN] = s[255]; // total == NE
}

__global__ __launch_bounds__(SCAN_BLK) void scan_phase3(const int* __restrict__ deg,
                                                        const int* __restrict__ bpre,
                                                        int* __restrict__ rowptr) {
  __shared__ int s[SCAN_BLK];
  int t = threadIdx.x;
  int i = blockIdx.x * SCAN_BLK + t;
  int v = (i < NN) ? deg[i] : 0;
  s[t] = v;
  __syncthreads();
  for (int off = 1; off < SCAN_BLK; off <<= 1) {
    int u = (t >= off) ? s[t - off] : 0;
    __syncthreads();
    s[t] += u;
    __syncthreads();
  }
  if (i < NN) rowptr[i] = bpre[blockIdx.x] + s[t] - v;
}

// ---- GEMM tile body (TH = float or bhalf h-input; bf16 x out) ----
// x[row][j] = bf16( sum_k (opt ns[row]*) h[row][k] * W[k][j] )   K = 128
// 64 rows x DO cols; 256 threads = 16rq x 16cq, 4x4 per col-half.
// hs[64][132] fp32 (padded: conflict-free b128 reads); wl[128][64] per half.
template <int DO, bool USE_NS, typename TH>
__device__ void gemm_body(const TH* __restrict__ h, const float* __restrict__ W,
                          const float* __restrict__ ns, bhalf* __restrict__ x,
                          int row0, float* hs, float* wl) {
  constexpr int CH = DO / 64;
  const int tid = threadIdx.x;

  if constexpr (sizeof(TH) == 4) {
    // fp32 h: 8 iters x float4 (4 floats/thread)
#pragma unroll
    for (int it = 0; it < 8; ++it) {
      int flat = it * 256 + tid;
      int row = flat >> 5;
      int c = flat & 31;
      int grow = row0 + row;
      float4 hv = make_float4(0.f, 0.f, 0.f, 0.f);
      float sc = 0.f;
      if (grow < NN) {
        hv = *reinterpret_cast<const float4*>(&h[(size_t)grow * 128 + c * 4]);
        sc = USE_NS ? ns[grow] : 1.0f;
      }
      float* d = &hs[row * 132 + c * 4];
      d[0] = hv.x * sc; d[1] = hv.y * sc; d[2] = hv.z * sc; d[3] = hv.w * sc;
    }
  } else {
    // bf16 h: 4 iters x uint4 (8 bf16/thread), expand to fp32 in LDS
#pragma unroll
    for (int it = 0; it < 4; ++it) {
      int flat = it * 256 + tid;     // 0..1023
      int row = flat >> 4;
      int c8 = (flat & 15) * 8;
      int grow = row0 + row;
      uint4 v = make_uint4(0u, 0u, 0u, 0u);
      float sc = 0.f;
      if (grow < NN) {
        v = *reinterpret_cast<const uint4*>(&h[(size_t)grow * 128 + c8]);
        sc = USE_NS ? ns[grow] : 1.0f;
      }
      float* d = &hs[row * 132 + c8];
      d[0] = blo(v.x) * sc; d[1] = bhi(v.x) * sc;
      d[2] = blo(v.y) * sc; d[3] = bhi(v.y) * sc;
      d[4] = blo(v.z) * sc; d[5] = bhi(v.z) * sc;
      d[6] = blo(v.w) * sc; d[7] = bhi(v.w) * sc;
    }
  }

  const int rq = tid >> 4;
  const int cq = tid & 15;

  for (int ch = 0; ch < CH; ++ch) {
    __syncthreads();  // ch=0: hs ready; ch>0: wl no longer being read
#pragma unroll
    for (int it = 0; it < 8; ++it) {
      int flat = it * 256 + tid;
      int k = flat >> 4;
      int c4 = flat & 15;
      *reinterpret_cast<float4*>(&wl[k * 64 + c4 * 4]) =
          *reinterpret_cast<const float4*>(&W[k * DO + ch * 64 + c4 * 4]);
    }
    __syncthreads();

    float acc[4][4] = {{0.f}};
#pragma unroll 4
    for (int k4 = 0; k4 < 32; ++k4) {
      float hv[4][4], wv[4][4];
#pragma unroll
      for (int i = 0; i < 4; ++i) {
        float4 t = *reinterpret_cast<const float4*>(&hs[(rq * 4 + i) * 132 + k4 * 4]);
        hv[i][0] = t.x; hv[i][1] = t.y; hv[i][2] = t.z; hv[i][3] = t.w;
      }
#pragma unroll
      for (int kk = 0; kk < 4; ++kk) {
        float4 t = *reinterpret_cast<const float4*>(&wl[(k4 * 4 + kk) * 64 + cq * 4]);
        wv[kk][0] = t.x; wv[kk][1] = t.y; wv[kk][2] = t.z; wv[kk][3] = t.w;
      }
#pragma unroll
      for (int i = 0; i < 4; ++i)
#pragma unroll
        for (int kk = 0; kk < 4; ++kk)
#pragma unroll
          for (int j = 0; j < 4; ++j)
            acc[i][j] = fmaf(hv[i][kk], wv[kk][j], acc[i][j]);
    }

#pragma unroll
    for (int i = 0; i < 4; ++i) {
      int row = row0 + rq * 4 + i;
      if (row < NN) {
        uint2 p;
        p.x = pack2(acc[i][0], acc[i][1]);
        p.y = pack2(acc[i][2], acc[i][3]);
        *reinterpret_cast<uint2*>(&x[(size_t)row * DO + ch * 64 + cq * 4]) = p;
      }
    }
  }
}

// Fused scatter + layer-0 GEMM: blocks [0,EB) do the atomic-free CSR fill
// (random 4B writes, latency-bound); blocks [EB, EB+GEMM_TILES) run x0 =
// h0 @ W0 tiles (unscaled; ns folded into gather-0). Complementary pipes.
__global__ __launch_bounds__(256, 2) void scatter_gemm0_kernel(
    const int* __restrict__ src, const int* __restrict__ dst,
    const int* __restrict__ le, const int* __restrict__ rowptr,
    int* __restrict__ col,
    const float* __restrict__ h, const float* __restrict__ W,
    bhalf* __restrict__ x) {
  __shared__ __align__(16) float hs[64 * 132];
  __shared__ __align__(16) float wl[128 * 64];
  if (blockIdx.x < EB) {
    int e = blockIdx.x * 256 + threadIdx.x;
    if (e < NE) col[rowptr[dst[e]] + le[e]] = src[e];
    return;
  }
  gemm_body<128, false, float>(h, W, nullptr, x, (blockIdx.x - EB) * 64, hs, wl);
}

template <int DO>
__global__ __launch_bounds__(256, 2) void gemm_ns(const bhalf* __restrict__ h,
                                                  const float* __restrict__ W,
                                                  const float* __restrict__ ns,
                                                  bhalf* __restrict__ x) {
  __shared__ __align__(16) float hs[64 * 132];
  __shared__ __align__(16) float wl[128 * 64];
  gemm_body<DO, true, bhalf>(h, W, ns, x, blockIdx.x * 64, hs, wl);
}

// bf16 gather: one wave per node. LPR = D/8 lanes cover a row (8 bf16/lane
// via uint4); EPW = 64/LPR edge slots, 2-deep unroll. fp32 accumulate;
// shfl_xor slot-combine; lanes < LPR write with nd/bias(/relu) fused.
// OUTBF: write bf16 uint4 (intermediate layers) vs fp32 2x float4 (final).
// NSRC (layer 0): per-edge ns[col] scale.
template <int D, bool RELU, bool NSRC, bool OUTBF>
__global__ __launch_bounds__(256) void gather_kernel(const bhalf* __restrict__ x,
                                                     const int* __restrict__ rowptr,
                                                     const int* __restrict__ col,
                                                     const float* __restrict__ nd,
                                                     const float* __restrict__ b,
                                                     const float* __restrict__ nsv,
                                                     void* __restrict__ outp) {
  constexpr int LPR = D / 8;     // 16 (D=128) or 8 (D=64)
  constexpr int EPW = 64 / LPR;  // 4 or 8
  const int wid = (blockIdx.x * blockDim.x + threadIdx.x) >> 6;
  const int lane = threadIdx.x & 63;
  if (wid >= NN) return;
  const int sub = lane / LPR;
  const int ci = (lane % LPR) * 8;
  const int beg = rowptr[wid];
  const int end = rowptr[wid + 1];

  float a[8];
#pragma unroll
  for (int k = 0; k < 8; ++k) a[k] = 0.f;

  int e = beg + sub;
  for (; e + EPW < end; e += 2 * EPW) {
    int c0 = col[e];
    int c1 = col[e + EPW];
    float s0 = NSRC ? nsv[c0] : 1.0f;
    float s1 = NSRC ? nsv[c1] : 1.0f;
    uint4 v0 = *reinterpret_cast<const uint4*>(&x[(size_t)c0 * D + ci]);
    uint4 v1 = *reinterpret_cast<const uint4*>(&x[(size_t)c1 * D + ci]);
    float f0[8], f1[8];
    f0[0] = blo(v0.x); f0[1] = bhi(v0.x); f0[2] = blo(v0.y); f0[3] = bhi(v0.y);
    f0[4] = blo(v0.z); f0[5] = bhi(v0.z); f0[6] = blo(v0.w); f0[7] = bhi(v0.w);
    f1[0] = blo(v1.x); f1[1] = bhi(v1.x); f1[2] = blo(v1.y); f1[3] = bhi(v1.y);
    f1[4] = blo(v1.z); f1[5] = bhi(v1.z); f1[6] = blo(v1.w); f1[7] = bhi(v1.w);
    if (NSRC) {
#pragma unroll
      for (int k = 0; k < 8; ++k) a[k] = fmaf(s0, f0[k], fmaf(s1, f1[k], a[k]));
    } else {
#pragma unroll
      for (int k = 0; k < 8; ++k) a[k] += f0[k] + f1[k];
    }
  }
  if (e < end) {
    int c0 = col[e];
    float s0 = NSRC ? nsv[c0] : 1.0f;
    uint4 v0 = *reinterpret_cast<const uint4*>(&x[(size_t)c0 * D + ci]);
    float f0[8];
    f0[0] = blo(v0.x); f0[1] = bhi(v0.x); f0[2] = blo(v0.y); f0[3] = bhi(v0.y);
    f0[4] = blo(v0.z); f0[5] = bhi(v0.z); f0[6] = blo(v0.w); f0[7] = bhi(v0.w);
    if (NSRC) {
#pragma unroll
      for (int k = 0; k < 8; ++k) a[k] = fmaf(s0, f0[k], a[k]);
    } else {
#pragma unroll
      for (int k = 0; k < 8; ++k) a[k] += f0[k];
    }
  }

#pragma unroll
  for (int off = LPR; off < 64; off <<= 1) {
#pragma unroll
    for (int k = 0; k < 8; ++k) a[k] += __shfl_xor(a[k], off, 64);
  }

  if (lane < LPR) {
    const float s = nd[wid];
    float4 b0 = *reinterpret_cast<const float4*>(&b[ci]);
    float4 b1 = *reinterpret_cast<const float4*>(&b[ci + 4]);
    float r[8];
    r[0] = fmaf(a[0], s, b0.x); r[1] = fmaf(a[1], s, b0.y);
    r[2] = fmaf(a[2], s, b0.z); r[3] = fmaf(a[3], s, b0.w);
    r[4] = fmaf(a[4], s, b1.x); r[5] = fmaf(a[5], s, b1.y);
    r[6] = fmaf(a[6], s, b1.z); r[7] = fmaf(a[7], s, b1.w);
    if (RELU) {
#pragma unroll
      for (int k = 0; k < 8; ++k) r[k] = fmaxf(r[k], 0.f);
    }
    if constexpr (OUTBF) {
      bhalf* out = (bhalf*)outp;
      uint4 p;
      p.x = pack2(r[0], r[1]);
      p.y = pack2(r[2], r[3]);
      p.z = pack2(r[4], r[5]);
      p.w = pack2(r[6], r[7]);
      *reinterpret_cast<uint4*>(&out[(size_t)wid * D + ci]) = p;
    } else {
      float* out = (float*)outp;
      *reinterpret_cast<float4*>(&out[(size_t)wid * D + ci]) =
          make_float4(r[0], r[1], r[2], r[3]);
      *reinterpret_cast<float4*>(&out[(size_t)wid * D + ci + 4]) =
          make_float4(r[4], r[5], r[6], r[7]);
    }
  }
}

}  // namespace

extern "C" void kernel_launch(void* const* d_in, const int* in_sizes, int n_in,
                              void* d_out, int out_size, void* d_ws, size_t ws_size,
                              hipStream_t stream) {
  const float* h0  = (const float*)d_in[0];
  const int*   src = (const int*)d_in[1];
  const int*   dst = (const int*)d_in[2];
  const float* W0 = (const float*)d_in[3];
  const float* b0 = (const float*)d_in[4];
  const float* W1 = (const float*)d_in[5];
  const float* b1 = (const float*)d_in[6];
  const float* W2 = (const float*)d_in[7];
  const float* b2 = (const float*)d_in[8];
  const float* W3 = (const float*)d_in[9];
  const float* b3 = (const float*)d_in[10];
  float* out = (float*)d_out;

  // workspace layout (256B aligned)
  char* w = (char*)d_ws;
  size_t off = 0;
  auto take = [&](size_t bytes) {
    char* p = w + off;
    off = (off + bytes + 255) & ~size_t(255);
    return p;
  };
  int*   deg_out = (int*)take(NN * 4);   // adjacent: one memset covers both
  int*   deg_in  = (int*)take(NN * 4);
  float* nsrc    = (float*)take(NN * 4);
  float* ndst    = (float*)take(NN * 4);
  int*   rowptr  = (int*)take((NN + 1) * 4);
  int*   le      = (int*)take(NE * 4);
  int*   col     = (int*)take(NE * 4);
  int*   bsum    = (int*)take(NBLK * 4);
  int*   bpre    = (int*)take(NBLK * 4);
  bhalf* xbuf    = (bhalf*)take((size_t)NN * 128 * 2);  // bf16 GEMM outputs
  bhalf* hbuf    = (bhalf*)take((size_t)NN * 128 * 2);  // bf16 gather outputs
  (void)ws_size; (void)in_sizes; (void)n_in; (void)out_size;

  // zero both degree arrays (contiguous)
  hipMemsetAsync(deg_out, 0, (size_t)((char*)nsrc - (char*)deg_out), stream);

  // 1) degree atomics at full-machine issue rate (nothing else on the fabric)
  deg_loc_kernel<<<EB, 256, 0, stream>>>(src, dst, deg_out, deg_in, le);
  // 2) scan chain
  scan1_norm<<<NBLK, SCAN_BLK, 0, stream>>>(deg_out, deg_in, bsum, nsrc, ndst);
  scan_phase2<<<1, 256, 0, stream>>>(bsum, bpre, rowptr);
  scan_phase3<<<NBLK, SCAN_BLK, 0, stream>>>(deg_in, bpre, rowptr);
  // 3) CSR fill + layer-0 GEMM fused (complementary pipes)
  scatter_gemm0_kernel<<<EB + GEMM_TILES, 256, 0, stream>>>(
      src, dst, le, rowptr, col, h0, W0, xbuf);

  const int GATHER_BLOCKS = (NN * 64 + 255) / 256;  // one wave per node

  // layer 0: x0 unscaled bf16 -> gather applies ns[col]; h1 bf16
  gather_kernel<128, true, true, true><<<GATHER_BLOCKS, 256, 0, stream>>>(
      xbuf, rowptr, col, ndst, b0, nsrc, hbuf);
  // layer 1
  gemm_ns<128><<<GEMM_TILES, 256, 0, stream>>>(hbuf, W1, nsrc, xbuf);
  gather_kernel<128, true, false, true><<<GATHER_BLOCKS, 256, 0, stream>>>(
      xbuf, rowptr, col, ndst, b1, nullptr, hbuf);
  // layer 2
  gemm_ns<128><<<GEMM_TILES, 256, 0, stream>>>(hbuf, W2, nsrc, xbuf);
  gather_kernel<128, true, false, true><<<GATHER_BLOCKS, 256, 0, stream>>>(
      xbuf, rowptr, col, ndst, b2, nullptr, hbuf);
  // layer 3: no relu, D=64, fp32 straight to d_out
  gemm_ns<64><<<GEMM_TILES, 256, 0, stream>>>(hbuf, W3, nsrc, xbuf);
  gather_kernel<64, false, false, false><<<GATHER_BLOCKS, 256, 0, stream>>>(
      xbuf, rowptr, col, ndst, b3, nullptr, out);
}

// Round 17
// 266.070 us; speedup vs baseline: 1.1967x; 1.1967x over previous
//
#include <hip/hip_runtime.h>

// GCN 4-layer forward on MI355X.
// Reference: h' = relu( norm_dst * segsum_{dst}( ((h*norm_src) @ W)[src] ) + b )
//
// Round 17: r14 base (best, 302us) + bf16-MFMA for gemm1/2/3.
//  - W1/W2/W3 transpose-converted once to Wt[j][k] bf16 (extra blocks on
//    scan1's grid — free). A-frags load 16B-contiguous from bf16 hbuf
//    (row=lane&15, k=(lane>>4)*8+i); B-frags from Wt (L1-resident); C/D per
//    m89 mapping; ns folded into the epilogue (row scale commutes). No LDS.
//  - gemm0 stays fp32-FMA inside fused0 (hidden under the ~65us atomic
//    drain; keeps h0 unquantized). r16's unfuse reverted (318us).

namespace {

constexpr int NN = 50000;      // nodes
constexpr int NE = 600000;     // edges
constexpr int SCAN_BLK = 256;
constexpr int NBLK = (NN + SCAN_BLK - 1) / SCAN_BLK;  // 196
constexpr int DEG_BLOCKS = 256;
constexpr int GEMM_TILES = (NN + 63) / 64;            // 782
constexpr int WCVT_ELEMS = 128 * 128 + 128 * 128 + 128 * 64;  // 40960
constexpr int WCVT_BLOCKS = WCVT_ELEMS / 256;                 // 160

typedef unsigned short bhalf;
typedef __attribute__((ext_vector_type(8))) short short8v;   // 8 bf16
typedef __attribute__((ext_vector_type(4))) float f32x4;

__device__ inline float blo(unsigned int v) {  // low bf16 of a packed word
  return __uint_as_float(v << 16);
}
__device__ inline float bhi(unsigned int v) {  // high bf16 of a packed word
  return __uint_as_float(v & 0xFFFF0000u);
}
__device__ inline unsigned int f2b_bits(float f) {  // RNE bf16 in high 16 bits
  unsigned int b = __float_as_uint(f);
  return b + 0x7FFFu + ((b >> 16) & 1u);
}
__device__ inline unsigned int pack2(float lo, float hi) {
  return (f2b_bits(lo) >> 16) | (f2b_bits(hi) & 0xFFFF0000u);
}
__device__ inline bhalf f2b(float f) { return (bhalf)(f2b_bits(f) >> 16); }

// --- scan phase 1 + norms (+ W transpose-convert on extra blocks) ---
__global__ __launch_bounds__(SCAN_BLK) void scan1_norm_wcvt(
    const int* __restrict__ dego, const int* __restrict__ degi,
    int* __restrict__ bsum, float* __restrict__ ns, float* __restrict__ nd,
    const float* __restrict__ W1, const float* __restrict__ W2,
    const float* __restrict__ W3, bhalf* __restrict__ wt1,
    bhalf* __restrict__ wt2, bhalf* __restrict__ wt3) {
  if (blockIdx.x >= NBLK) {
    // Wt[j][k] = bf16(W[k][j]); flat = j*128 + k per matrix
    int flat = (blockIdx.x - NBLK) * 256 + threadIdx.x;
    if (flat < 16384) {
      int j = flat >> 7, k = flat & 127;
      wt1[flat] = f2b(W1[k * 128 + j]);
    } else if (flat < 32768) {
      int f = flat - 16384;
      int j = f >> 7, k = f & 127;
      wt2[f] = f2b(W2[k * 128 + j]);
    } else {
      int f = flat - 32768;
      int j = f >> 7, k = f & 127;
      wt3[f] = f2b(W3[k * 64 + j]);
    }
    return;
  }
  __shared__ int ws[SCAN_BLK / 64];
  int i = blockIdx.x * SCAN_BLK + threadIdx.x;
  int v = 0;
  if (i < NN) {
    int din = degi[i];
    int dout = dego[i];
    v = din;
    int a = dout < 1 ? 1 : dout;
    int b = din < 1 ? 1 : din;
    ns[i] = 1.0f / sqrtf((float)a);
    nd[i] = 1.0f / sqrtf((float)b);
  }
#pragma unroll
  for (int off = 32; off; off >>= 1) v += __shfl_down(v, off, 64);
  int lane = threadIdx.x & 63, w = threadIdx.x >> 6;
  if (lane == 0) ws[w] = v;
  __syncthreads();
  if (threadIdx.x == 0) {
    int s = 0;
#pragma unroll
    for (int k = 0; k < SCAN_BLK / 64; ++k) s += ws[k];
    bsum[blockIdx.x] = s;
  }
}

__global__ __launch_bounds__(256) void scan_phase2(const int* __restrict__ bsum,
                                                   int* __restrict__ bpre,
                                                   int* __restrict__ rowptr) {
  __shared__ int s[256];
  int t = threadIdx.x;
  int v = (t < NBLK) ? bsum[t] : 0;
  s[t] = v;
  __syncthreads();
  for (int off = 1; off < 256; off <<= 1) {
    int u = (t >= off) ? s[t - off] : 0;
    __syncthreads();
    s[t] += u;
    __syncthreads();
  }
  if (t < NBLK) bpre[t] = s[t] - v;  // exclusive
  if (t == 255) rowptr[NN] = s[255]; // total == NE
}

__global__ __launch_bounds__(SCAN_BLK) void scan_phase3(const int* __restrict__ deg,
                                                        const int* __restrict__ bpre,
                                                        int* __restrict__ rowptr) {
  __shared__ int s[SCAN_BLK];
  int t = threadIdx.x;
  int i = blockIdx.x * SCAN_BLK + t;
  int v = (i < NN) ? deg[i] : 0;
  s[t] = v;
  __syncthreads();
  for (int off = 1; off < SCAN_BLK; off <<= 1) {
    int u = (t >= off) ? s[t - off] : 0;
    __syncthreads();
    s[t] += u;
    __syncthreads();
  }
  if (i < NN) rowptr[i] = bpre[blockIdx.x] + s[t] - v;
}

// atomic-free CSR fill using le slots recorded during counting
__global__ void scatter_kernel(const int* __restrict__ src, const int* __restrict__ dst,
                               const int* __restrict__ le, const int* __restrict__ rowptr,
                               int* __restrict__ col) {
  int e = blockIdx.x * blockDim.x + threadIdx.x;
  if (e < NE) col[rowptr[dst[e]] + le[e]] = src[e];
}

// ---- fp32-FMA GEMM tile body for layer 0 (fp32 h in, bf16 x out) ----
__device__ void gemm0_body(const float* __restrict__ h, const float* __restrict__ W,
                           bhalf* __restrict__ x, int row0, float* hs, float* wl) {
  const int tid = threadIdx.x;
#pragma unroll
  for (int it = 0; it < 8; ++it) {
    int flat = it * 256 + tid;
    int row = flat >> 5;
    int c = flat & 31;
    int grow = row0 + row;
    float4 hv = make_float4(0.f, 0.f, 0.f, 0.f);
    if (grow < NN)
      hv = *reinterpret_cast<const float4*>(&h[(size_t)grow * 128 + c * 4]);
    float* d = &hs[row * 132 + c * 4];
    d[0] = hv.x; d[1] = hv.y; d[2] = hv.z; d[3] = hv.w;
  }

  const int rq = tid >> 4;
  const int cq = tid & 15;

  for (int ch = 0; ch < 2; ++ch) {
    __syncthreads();
#pragma unroll
    for (int it = 0; it < 8; ++it) {
      int flat = it * 256 + tid;
      int k = flat >> 4;
      int c4 = flat & 15;
      *reinterpret_cast<float4*>(&wl[k * 64 + c4 * 4]) =
          *reinterpret_cast<const float4*>(&W[k * 128 + ch * 64 + c4 * 4]);
    }
    __syncthreads();

    float acc[4][4] = {{0.f}};
#pragma unroll 4
    for (int k4 = 0; k4 < 32; ++k4) {
      float hv[4][4], wv[4][4];
#pragma unroll
      for (int i = 0; i < 4; ++i) {
        float4 t = *reinterpret_cast<const float4*>(&hs[(rq * 4 + i) * 132 + k4 * 4]);
        hv[i][0] = t.x; hv[i][1] = t.y; hv[i][2] = t.z; hv[i][3] = t.w;
      }
#pragma unroll
      for (int kk = 0; kk < 4; ++kk) {
        float4 t = *reinterpret_cast<const float4*>(&wl[(k4 * 4 + kk) * 64 + cq * 4]);
        wv[kk][0] = t.x; wv[kk][1] = t.y; wv[kk][2] = t.z; wv[kk][3] = t.w;
      }
#pragma unroll
      for (int i = 0; i < 4; ++i)
#pragma unroll
        for (int kk = 0; kk < 4; ++kk)
#pragma unroll
          for (int j = 0; j < 4; ++j)
            acc[i][j] = fmaf(hv[i][kk], wv[kk][j], acc[i][j]);
    }

#pragma unroll
    for (int i = 0; i < 4; ++i) {
      int row = row0 + rq * 4 + i;
      if (row < NN) {
        uint2 p;
        p.x = pack2(acc[i][0], acc[i][1]);
        p.y = pack2(acc[i][2], acc[i][3]);
        *reinterpret_cast<uint2*>(&x[(size_t)row * 128 + ch * 64 + cq * 4]) = p;
      }
    }
  }
}

// Fused (r14 structure, 79us): blocks [0,DEG_BLOCKS) run degree counting +
// le (grid-stride atomics from t=0); rest run layer-0 GEMM tiles (x0 = h0@W0
// unscaled; ns folded into gather-0).
__global__ __launch_bounds__(256, 2) void gemm0_deg_kernel(
    const float* __restrict__ h, const float* __restrict__ W,
    bhalf* __restrict__ x,
    const int* __restrict__ src, const int* __restrict__ dst,
    int* __restrict__ dego, int* __restrict__ degi, int* __restrict__ le) {
  __shared__ __align__(16) float hs[64 * 132];
  __shared__ __align__(16) float wl[128 * 64];
  if (blockIdx.x < DEG_BLOCKS) {
    const int stride = DEG_BLOCKS * 256;
    for (int e = blockIdx.x * 256 + threadIdx.x; e < NE; e += stride) {
      atomicAdd(&dego[src[e]], 1);
      le[e] = atomicAdd(&degi[dst[e]], 1);
    }
    return;
  }
  gemm0_body(h, W, x, (blockIdx.x - DEG_BLOCKS) * 64, hs, wl);
}

// ---- bf16 MFMA GEMM: x[row][j] = bf16( ns[row] * sum_k h[row][k]*W[k][j] )
// One wave per 16-row tile (50000 = 16*3125 exact). A-frag: row=lane&15,
// k=(lane>>4)*8+i -> 16B contiguous load from bf16 h. B-frag from Wt[j][k]
// (col=lane&15, same k window) -> 16B load, L1-resident (<=32KB). K-loop 4.
// C/D: col=lane&15, row=(lane>>4)*4+reg (m89). ns applied in epilogue.
template <int DO>
__global__ __launch_bounds__(256, 2) void gemm_mfma(const bhalf* __restrict__ h,
                                                    const bhalf* __restrict__ wt,
                                                    const float* __restrict__ ns,
                                                    bhalf* __restrict__ x) {
  constexpr int CF = DO / 16;  // col fragments: 8 or 4
  const int lane = threadIdx.x & 63;
  const int wv = threadIdx.x >> 6;
  const int tile = blockIdx.x * 4 + wv;
  if (tile >= NN / 16) return;
  const int row0 = tile * 16;
  const size_t arow = (size_t)(row0 + (lane & 15)) * 128;
  const int koff = (lane >> 4) * 8;
  const int bcol = lane & 15;

  f32x4 acc[CF];
#pragma unroll
  for (int cf = 0; cf < CF; ++cf) acc[cf] = (f32x4){0.f, 0.f, 0.f, 0.f};

#pragma unroll
  for (int ks = 0; ks < 4; ++ks) {
    const int k0 = ks * 32 + koff;
    short8v av = *reinterpret_cast<const short8v*>(&h[arow + k0]);
#pragma unroll
    for (int cf = 0; cf < CF; ++cf) {
      short8v bv = *reinterpret_cast<const short8v*>(
          &wt[(size_t)(cf * 16 + bcol) * 128 + k0]);
      acc[cf] = __builtin_amdgcn_mfma_f32_16x16x32_bf16(av, bv, acc[cf], 0, 0, 0);
    }
  }

  // epilogue: row = row0 + (lane>>4)*4 + r, col = cf*16 + (lane&15)
  const int crow = row0 + ((lane >> 4) << 2);
  float nsv[4];
#pragma unroll
  for (int r = 0; r < 4; ++r) nsv[r] = ns[crow + r];
#pragma unroll
  for (int cf = 0; cf < CF; ++cf) {
#pragma unroll
    for (int r = 0; r < 4; ++r) {
      x[(size_t)(crow + r) * DO + cf * 16 + bcol] = f2b(acc[cf][r] * nsv[r]);
    }
  }
}

// bf16 gather: one wave per node (r14, unchanged). LPR = D/8 lanes cover a
// row (8 bf16/lane via uint4); EPW edge slots, 2-deep. fp32 accum; shfl_xor
// combine; nd/bias(/relu) fused. OUTBF: bf16 out vs fp32 (final). NSRC:
// per-edge ns[col] scale (layer 0).
template <int D, bool RELU, bool NSRC, bool OUTBF>
__global__ __launch_bounds__(256) void gather_kernel(const bhalf* __restrict__ x,
                                                     const int* __restrict__ rowptr,
                                                     const int* __restrict__ col,
                                                     const float* __restrict__ nd,
                                                     const float* __restrict__ b,
                                                     const float* __restrict__ nsv,
                                                     void* __restrict__ outp) {
  constexpr int LPR = D / 8;     // 16 (D=128) or 8 (D=64)
  constexpr int EPW = 64 / LPR;  // 4 or 8
  const int wid = (blockIdx.x * blockDim.x + threadIdx.x) >> 6;
  const int lane = threadIdx.x & 63;
  if (wid >= NN) return;
  const int sub = lane / LPR;
  const int ci = (lane % LPR) * 8;
  const int beg = rowptr[wid];
  const int end = rowptr[wid + 1];

  float a[8];
#pragma unroll
  for (int k = 0; k < 8; ++k) a[k] = 0.f;

  int e = beg + sub;
  for (; e + EPW < end; e += 2 * EPW) {
    int c0 = col[e];
    int c1 = col[e + EPW];
    float s0 = NSRC ? nsv[c0] : 1.0f;
    float s1 = NSRC ? nsv[c1] : 1.0f;
    uint4 v0 = *reinterpret_cast<const uint4*>(&x[(size_t)c0 * D + ci]);
    uint4 v1 = *reinterpret_cast<const uint4*>(&x[(size_t)c1 * D + ci]);
    float f0[8], f1[8];
    f0[0] = blo(v0.x); f0[1] = bhi(v0.x); f0[2] = blo(v0.y); f0[3] = bhi(v0.y);
    f0[4] = blo(v0.z); f0[5] = bhi(v0.z); f0[6] = blo(v0.w); f0[7] = bhi(v0.w);
    f1[0] = blo(v1.x); f1[1] = bhi(v1.x); f1[2] = blo(v1.y); f1[3] = bhi(v1.y);
    f1[4] = blo(v1.z); f1[5] = bhi(v1.z); f1[6] = blo(v1.w); f1[7] = bhi(v1.w);
    if (NSRC) {
#pragma unroll
      for (int k = 0; k < 8; ++k) a[k] = fmaf(s0, f0[k], fmaf(s1, f1[k], a[k]));
    } else {
#pragma unroll
      for (int k = 0; k < 8; ++k) a[k] += f0[k] + f1[k];
    }
  }
  if (e < end) {
    int c0 = col[e];
    float s0 = NSRC ? nsv[c0] : 1.0f;
    uint4 v0 = *reinterpret_cast<const uint4*>(&x[(size_t)c0 * D + ci]);
    float f0[8];
    f0[0] = blo(v0.x); f0[1] = bhi(v0.x); f0[2] = blo(v0.y); f0[3] = bhi(v0.y);
    f0[4] = blo(v0.z); f0[5] = bhi(v0.z); f0[6] = blo(v0.w); f0[7] = bhi(v0.w);
    if (NSRC) {
#pragma unroll
      for (int k = 0; k < 8; ++k) a[k] = fmaf(s0, f0[k], a[k]);
    } else {
#pragma unroll
      for (int k = 0; k < 8; ++k) a[k] += f0[k];
    }
  }

#pragma unroll
  for (int off = LPR; off < 64; off <<= 1) {
#pragma unroll
    for (int k = 0; k < 8; ++k) a[k] += __shfl_xor(a[k], off, 64);
  }

  if (lane < LPR) {
    const float s = nd[wid];
    float4 b0 = *reinterpret_cast<const float4*>(&b[ci]);
    float4 b1 = *reinterpret_cast<const float4*>(&b[ci + 4]);
    float r[8];
    r[0] = fmaf(a[0], s, b0.x); r[1] = fmaf(a[1], s, b0.y);
    r[2] = fmaf(a[2], s, b0.z); r[3] = fmaf(a[3], s, b0.w);
    r[4] = fmaf(a[4], s, b1.x); r[5] = fmaf(a[5], s, b1.y);
    r[6] = fmaf(a[6], s, b1.z); r[7] = fmaf(a[7], s, b1.w);
    if (RELU) {
#pragma unroll
      for (int k = 0; k < 8; ++k) r[k] = fmaxf(r[k], 0.f);
    }
    if constexpr (OUTBF) {
      bhalf* out = (bhalf*)outp;
      uint4 p;
      p.x = pack2(r[0], r[1]);
      p.y = pack2(r[2], r[3]);
      p.z = pack2(r[4], r[5]);
      p.w = pack2(r[6], r[7]);
      *reinterpret_cast<uint4*>(&out[(size_t)wid * D + ci]) = p;
    } else {
      float* out = (float*)outp;
      *reinterpret_cast<float4*>(&out[(size_t)wid * D + ci]) =
          make_float4(r[0], r[1], r[2], r[3]);
      *reinterpret_cast<float4*>(&out[(size_t)wid * D + ci + 4]) =
          make_float4(r[4], r[5], r[6], r[7]);
    }
  }
}

}  // namespace

extern "C" void kernel_launch(void* const* d_in, const int* in_sizes, int n_in,
                              void* d_out, int out_size, void* d_ws, size_t ws_size,
                              hipStream_t stream) {
  const float* h0  = (const float*)d_in[0];
  const int*   src = (const int*)d_in[1];
  const int*   dst = (const int*)d_in[2];
  const float* W0 = (const float*)d_in[3];
  const float* b0 = (const float*)d_in[4];
  const float* W1 = (const float*)d_in[5];
  const float* b1 = (const float*)d_in[6];
  const float* W2 = (const float*)d_in[7];
  const float* b2 = (const float*)d_in[8];
  const float* W3 = (const float*)d_in[9];
  const float* b3 = (const float*)d_in[10];
  float* out = (float*)d_out;

  // workspace layout (256B aligned)
  char* w = (char*)d_ws;
  size_t off = 0;
  auto take = [&](size_t bytes) {
    char* p = w + off;
    off = (off + bytes + 255) & ~size_t(255);
    return p;
  };
  int*   deg_out = (int*)take(NN * 4);   // adjacent: one memset covers both
  int*   deg_in  = (int*)take(NN * 4);
  float* nsrc    = (float*)take(NN * 4);
  float* ndst    = (float*)take(NN * 4);
  int*   rowptr  = (int*)take((NN + 1) * 4);
  int*   le      = (int*)take(NE * 4);
  int*   col     = (int*)take(NE * 4);
  int*   bsum    = (int*)take(NBLK * 4);
  int*   bpre    = (int*)take(NBLK * 4);
  bhalf* xbuf    = (bhalf*)take((size_t)NN * 128 * 2);  // bf16 GEMM outputs
  bhalf* hbuf    = (bhalf*)take((size_t)NN * 128 * 2);  // bf16 gather outputs
  bhalf* wt1     = (bhalf*)take(128 * 128 * 2);         // W1^T bf16
  bhalf* wt2     = (bhalf*)take(128 * 128 * 2);         // W2^T bf16
  bhalf* wt3     = (bhalf*)take(64 * 128 * 2);          // W3^T bf16
  (void)ws_size; (void)in_sizes; (void)n_in; (void)out_size;

  // zero both degree arrays (contiguous)
  hipMemsetAsync(deg_out, 0, (size_t)((char*)nsrc - (char*)deg_out), stream);

  const int EB = (NE + 255) / 256;

  // fused: degree atomics (blocks 0..255) + layer-0 GEMM x0 = h0@W0 (rest)
  gemm0_deg_kernel<<<DEG_BLOCKS + GEMM_TILES, 256, 0, stream>>>(
      h0, W0, xbuf, src, dst, deg_out, deg_in, le);
  // scan phase1 + norms + W->Wt bf16 convert (extra blocks, independent)
  scan1_norm_wcvt<<<NBLK + WCVT_BLOCKS, SCAN_BLK, 0, stream>>>(
      deg_out, deg_in, bsum, nsrc, ndst, W1, W2, W3, wt1, wt2, wt3);
  scan_phase2<<<1, 256, 0, stream>>>(bsum, bpre, rowptr);
  scan_phase3<<<NBLK, SCAN_BLK, 0, stream>>>(deg_in, bpre, rowptr);
  scatter_kernel<<<EB, 256, 0, stream>>>(src, dst, le, rowptr, col);

  const int GATHER_BLOCKS = (NN * 64 + 255) / 256;  // one wave per node
  const int MFMA_BLOCKS = (NN / 16 + 3) / 4;        // 782 (4 wave-tiles each)

  // layer 0: x0 unscaled bf16 -> gather applies ns[col]; h1 bf16
  gather_kernel<128, true, true, true><<<GATHER_BLOCKS, 256, 0, stream>>>(
      xbuf, rowptr, col, ndst, b0, nsrc, hbuf);
  // layer 1 (MFMA)
  gemm_mfma<128><<<MFMA_BLOCKS, 256, 0, stream>>>(hbuf, wt1, nsrc, xbuf);
  gather_kernel<128, true, false, true><<<GATHER_BLOCKS, 256, 0, stream>>>(
      xbuf, rowptr, col, ndst, b1, nullptr, hbuf);
  // layer 2 (MFMA)
  gemm_mfma<128><<<MFMA_BLOCKS, 256, 0, stream>>>(hbuf, wt2, nsrc, xbuf);
  gather_kernel<128, true, false, true><<<GATHER_BLOCKS, 256, 0, stream>>>(
      xbuf, rowptr, col, ndst, b2, nullptr, hbuf);
  // layer 3 (MFMA, DO=64): no relu, fp32 straight to d_out
  gemm_mfma<64><<<MFMA_BLOCKS, 256, 0, stream>>>(hbuf, wt3, nsrc, xbuf);
  gather_kernel<64, false, false, false><<<GATHER_BLOCKS, 256, 0, stream>>>(
      xbuf, rowptr, col, ndst, b3, nullptr, out);
}

// Round 18
// 250.451 us; speedup vs baseline: 1.2714x; 1.0624x over previous
//
#include <hip/hip_runtime.h>

// GCN 4-layer forward on MI355X.
// Reference: h' = relu( norm_dst * segsum_{dst}( ((h*norm_src) @ W)[src] ) + b )
//
// Round 18: r17 (266us) + dual-node gather. Gathers are L3-latency-bound
// (~4.3 TB/s effective on a 12.8MB L3-resident buffer): one node per wave =
// ~3 short dependent load bursts. Two nodes per wave with interleaved,
// predicated edge loops give 2 independent chains/lane -> ~2x outstanding
// lines. Writers: lanes [0,LPR) node0, [LPR,2LPR) node1. Math unchanged.

namespace {

constexpr int NN = 50000;      // nodes
constexpr int NE = 600000;     // edges
constexpr int SCAN_BLK = 256;
constexpr int NBLK = (NN + SCAN_BLK - 1) / SCAN_BLK;  // 196
constexpr int DEG_BLOCKS = 256;
constexpr int GEMM_TILES = (NN + 63) / 64;            // 782
constexpr int WCVT_ELEMS = 128 * 128 + 128 * 128 + 128 * 64;  // 40960
constexpr int WCVT_BLOCKS = WCVT_ELEMS / 256;                 // 160

typedef unsigned short bhalf;
typedef __attribute__((ext_vector_type(8))) short short8v;   // 8 bf16
typedef __attribute__((ext_vector_type(4))) float f32x4;

__device__ inline float blo(unsigned int v) {  // low bf16 of a packed word
  return __uint_as_float(v << 16);
}
__device__ inline float bhi(unsigned int v) {  // high bf16 of a packed word
  return __uint_as_float(v & 0xFFFF0000u);
}
__device__ inline unsigned int f2b_bits(float f) {  // RNE bf16 in high 16 bits
  unsigned int b = __float_as_uint(f);
  return b + 0x7FFFu + ((b >> 16) & 1u);
}
__device__ inline unsigned int pack2(float lo, float hi) {
  return (f2b_bits(lo) >> 16) | (f2b_bits(hi) & 0xFFFF0000u);
}
__device__ inline bhalf f2b(float f) { return (bhalf)(f2b_bits(f) >> 16); }

// --- scan phase 1 + norms (+ W transpose-convert on extra blocks) ---
__global__ __launch_bounds__(SCAN_BLK) void scan1_norm_wcvt(
    const int* __restrict__ dego, const int* __restrict__ degi,
    int* __restrict__ bsum, float* __restrict__ ns, float* __restrict__ nd,
    const float* __restrict__ W1, const float* __restrict__ W2,
    const float* __restrict__ W3, bhalf* __restrict__ wt1,
    bhalf* __restrict__ wt2, bhalf* __restrict__ wt3) {
  if (blockIdx.x >= NBLK) {
    // Wt[j][k] = bf16(W[k][j]); flat = j*128 + k per matrix
    int flat = (blockIdx.x - NBLK) * 256 + threadIdx.x;
    if (flat < 16384) {
      int j = flat >> 7, k = flat & 127;
      wt1[flat] = f2b(W1[k * 128 + j]);
    } else if (flat < 32768) {
      int f = flat - 16384;
      int j = f >> 7, k = f & 127;
      wt2[f] = f2b(W2[k * 128 + j]);
    } else {
      int f = flat - 32768;
      int j = f >> 7, k = f & 127;
      wt3[f] = f2b(W3[k * 64 + j]);
    }
    return;
  }
  __shared__ int ws[SCAN_BLK / 64];
  int i = blockIdx.x * SCAN_BLK + threadIdx.x;
  int v = 0;
  if (i < NN) {
    int din = degi[i];
    int dout = dego[i];
    v = din;
    int a = dout < 1 ? 1 : dout;
    int b = din < 1 ? 1 : din;
    ns[i] = 1.0f / sqrtf((float)a);
    nd[i] = 1.0f / sqrtf((float)b);
  }
#pragma unroll
  for (int off = 32; off; off >>= 1) v += __shfl_down(v, off, 64);
  int lane = threadIdx.x & 63, w = threadIdx.x >> 6;
  if (lane == 0) ws[w] = v;
  __syncthreads();
  if (threadIdx.x == 0) {
    int s = 0;
#pragma unroll
    for (int k = 0; k < SCAN_BLK / 64; ++k) s += ws[k];
    bsum[blockIdx.x] = s;
  }
}

__global__ __launch_bounds__(256) void scan_phase2(const int* __restrict__ bsum,
                                                   int* __restrict__ bpre,
                                                   int* __restrict__ rowptr) {
  __shared__ int s[256];
  int t = threadIdx.x;
  int v = (t < NBLK) ? bsum[t] : 0;
  s[t] = v;
  __syncthreads();
  for (int off = 1; off < 256; off <<= 1) {
    int u = (t >= off) ? s[t - off] : 0;
    __syncthreads();
    s[t] += u;
    __syncthreads();
  }
  if (t < NBLK) bpre[t] = s[t] - v;  // exclusive
  if (t == 255) rowptr[NN] = s[255]; // total == NE
}

__global__ __launch_bounds__(SCAN_BLK) void scan_phase3(const int* __restrict__ deg,
                                                        const int* __restrict__ bpre,
                                                        int* __restrict__ rowptr) {
  __shared__ int s[SCAN_BLK];
  int t = threadIdx.x;
  int i = blockIdx.x * SCAN_BLK + t;
  int v = (i < NN) ? deg[i] : 0;
  s[t] = v;
  __syncthreads();
  for (int off = 1; off < SCAN_BLK; off <<= 1) {
    int u = (t >= off) ? s[t - off] : 0;
    __syncthreads();
    s[t] += u;
    __syncthreads();
  }
  if (i < NN) rowptr[i] = bpre[blockIdx.x] + s[t] - v;
}

// atomic-free CSR fill using le slots recorded during counting
__global__ void scatter_kernel(const int* __restrict__ src, const int* __restrict__ dst,
                               const int* __restrict__ le, const int* __restrict__ rowptr,
                               int* __restrict__ col) {
  int e = blockIdx.x * blockDim.x + threadIdx.x;
  if (e < NE) col[rowptr[dst[e]] + le[e]] = src[e];
}

// ---- fp32-FMA GEMM tile body for layer 0 (fp32 h in, bf16 x out) ----
__device__ void gemm0_body(const float* __restrict__ h, const float* __restrict__ W,
                           bhalf* __restrict__ x, int row0, float* hs, float* wl) {
  const int tid = threadIdx.x;
#pragma unroll
  for (int it = 0; it < 8; ++it) {
    int flat = it * 256 + tid;
    int row = flat >> 5;
    int c = flat & 31;
    int grow = row0 + row;
    float4 hv = make_float4(0.f, 0.f, 0.f, 0.f);
    if (grow < NN)
      hv = *reinterpret_cast<const float4*>(&h[(size_t)grow * 128 + c * 4]);
    float* d = &hs[row * 132 + c * 4];
    d[0] = hv.x; d[1] = hv.y; d[2] = hv.z; d[3] = hv.w;
  }

  const int rq = tid >> 4;
  const int cq = tid & 15;

  for (int ch = 0; ch < 2; ++ch) {
    __syncthreads();
#pragma unroll
    for (int it = 0; it < 8; ++it) {
      int flat = it * 256 + tid;
      int k = flat >> 4;
      int c4 = flat & 15;
      *reinterpret_cast<float4*>(&wl[k * 64 + c4 * 4]) =
          *reinterpret_cast<const float4*>(&W[k * 128 + ch * 64 + c4 * 4]);
    }
    __syncthreads();

    float acc[4][4] = {{0.f}};
#pragma unroll 4
    for (int k4 = 0; k4 < 32; ++k4) {
      float hv[4][4], wv[4][4];
#pragma unroll
      for (int i = 0; i < 4; ++i) {
        float4 t = *reinterpret_cast<const float4*>(&hs[(rq * 4 + i) * 132 + k4 * 4]);
        hv[i][0] = t.x; hv[i][1] = t.y; hv[i][2] = t.z; hv[i][3] = t.w;
      }
#pragma unroll
      for (int kk = 0; kk < 4; ++kk) {
        float4 t = *reinterpret_cast<const float4*>(&wl[(k4 * 4 + kk) * 64 + cq * 4]);
        wv[kk][0] = t.x; wv[kk][1] = t.y; wv[kk][2] = t.z; wv[kk][3] = t.w;
      }
#pragma unroll
      for (int i = 0; i < 4; ++i)
#pragma unroll
        for (int kk = 0; kk < 4; ++kk)
#pragma unroll
          for (int j = 0; j < 4; ++j)
            acc[i][j] = fmaf(hv[i][kk], wv[kk][j], acc[i][j]);
    }

#pragma unroll
    for (int i = 0; i < 4; ++i) {
      int row = row0 + rq * 4 + i;
      if (row < NN) {
        uint2 p;
        p.x = pack2(acc[i][0], acc[i][1]);
        p.y = pack2(acc[i][2], acc[i][3]);
        *reinterpret_cast<uint2*>(&x[(size_t)row * 128 + ch * 64 + cq * 4]) = p;
      }
    }
  }
}

// Fused (r14 structure, 79us): blocks [0,DEG_BLOCKS) run degree counting +
// le (grid-stride atomics from t=0); rest run layer-0 GEMM tiles (x0 = h0@W0
// unscaled; ns folded into gather-0).
__global__ __launch_bounds__(256, 2) void gemm0_deg_kernel(
    const float* __restrict__ h, const float* __restrict__ W,
    bhalf* __restrict__ x,
    const int* __restrict__ src, const int* __restrict__ dst,
    int* __restrict__ dego, int* __restrict__ degi, int* __restrict__ le) {
  __shared__ __align__(16) float hs[64 * 132];
  __shared__ __align__(16) float wl[128 * 64];
  if (blockIdx.x < DEG_BLOCKS) {
    const int stride = DEG_BLOCKS * 256;
    for (int e = blockIdx.x * 256 + threadIdx.x; e < NE; e += stride) {
      atomicAdd(&dego[src[e]], 1);
      le[e] = atomicAdd(&degi[dst[e]], 1);
    }
    return;
  }
  gemm0_body(h, W, x, (blockIdx.x - DEG_BLOCKS) * 64, hs, wl);
}

// ---- bf16 MFMA GEMM (r17, verified): one wave per 16-row tile ----
template <int DO>
__global__ __launch_bounds__(256, 2) void gemm_mfma(const bhalf* __restrict__ h,
                                                    const bhalf* __restrict__ wt,
                                                    const float* __restrict__ ns,
                                                    bhalf* __restrict__ x) {
  constexpr int CF = DO / 16;  // col fragments: 8 or 4
  const int lane = threadIdx.x & 63;
  const int wv = threadIdx.x >> 6;
  const int tile = blockIdx.x * 4 + wv;
  if (tile >= NN / 16) return;
  const int row0 = tile * 16;
  const size_t arow = (size_t)(row0 + (lane & 15)) * 128;
  const int koff = (lane >> 4) * 8;
  const int bcol = lane & 15;

  f32x4 acc[CF];
#pragma unroll
  for (int cf = 0; cf < CF; ++cf) acc[cf] = (f32x4){0.f, 0.f, 0.f, 0.f};

#pragma unroll
  for (int ks = 0; ks < 4; ++ks) {
    const int k0 = ks * 32 + koff;
    short8v av = *reinterpret_cast<const short8v*>(&h[arow + k0]);
#pragma unroll
    for (int cf = 0; cf < CF; ++cf) {
      short8v bv = *reinterpret_cast<const short8v*>(
          &wt[(size_t)(cf * 16 + bcol) * 128 + k0]);
      acc[cf] = __builtin_amdgcn_mfma_f32_16x16x32_bf16(av, bv, acc[cf], 0, 0, 0);
    }
  }

  const int crow = row0 + ((lane >> 4) << 2);
  float nsv[4];
#pragma unroll
  for (int r = 0; r < 4; ++r) nsv[r] = ns[crow + r];
#pragma unroll
  for (int cf = 0; cf < CF; ++cf) {
#pragma unroll
    for (int r = 0; r < 4; ++r) {
      x[(size_t)(crow + r) * DO + cf * 16 + bcol] = f2b(acc[cf][r] * nsv[r]);
    }
  }
}

// ---- Dual-node bf16 gather ----
// One wave per TWO nodes (n0=2*wid, n1=2*wid+1; NN even). LPR = D/8 lanes
// cover a row (8 bf16/lane via uint4); EPW = 64/LPR edge slots per node.
// Per iteration: two independent predicated chains (clamped index + s=0 for
// exhausted cursors) -> 2x outstanding loads vs single-node. fp32 accum;
// shfl_xor butterfly replicates sums to all lanes; lanes [0,LPR) write n0,
// [LPR,2LPR) write n1. OUTBF: bf16 out vs fp32 (final). NSRC: ns[col] scale.
template <int D, bool RELU, bool NSRC, bool OUTBF>
__global__ __launch_bounds__(256) void gather2_kernel(const bhalf* __restrict__ x,
                                                      const int* __restrict__ rowptr,
                                                      const int* __restrict__ col,
                                                      const float* __restrict__ nd,
                                                      const float* __restrict__ b,
                                                      const float* __restrict__ nsv,
                                                      void* __restrict__ outp) {
  constexpr int LPR = D / 8;     // 16 (D=128) or 8 (D=64)
  constexpr int EPW = 64 / LPR;  // 4 or 8
  const int wid = (blockIdx.x * blockDim.x + threadIdx.x) >> 6;
  const int lane = threadIdx.x & 63;
  const int n0 = wid * 2;
  if (n0 >= NN) return;
  const int n1 = n0 + 1;
  const int sub = lane / LPR;
  const int ci = (lane % LPR) * 8;
  const int beg0 = rowptr[n0], end0 = rowptr[n0 + 1];
  const int beg1 = rowptr[n1], end1 = rowptr[n1 + 1];
  int e0 = beg0 + sub;
  int e1 = beg1 + sub;
  const int d0 = end0 - beg0, d1 = end1 - beg1;
  const int iters = ((d0 > d1 ? d0 : d1) + EPW - 1) / EPW;  // wave-uniform

  float a0[8], a1[8];
#pragma unroll
  for (int k = 0; k < 8; ++k) { a0[k] = 0.f; a1[k] = 0.f; }

#pragma unroll 2
  for (int it = 0; it < iters; ++it) {
    const bool p0 = e0 < end0;
    const bool p1 = e1 < end1;
    const int ee0 = p0 ? e0 : 0;      // clamped: col[0] is a valid address
    const int ee1 = p1 ? e1 : 0;
    const int c0 = col[ee0];
    const int c1 = col[ee1];
    const float s0 = p0 ? (NSRC ? nsv[c0] : 1.0f) : 0.0f;
    const float s1 = p1 ? (NSRC ? nsv[c1] : 1.0f) : 0.0f;
    const uint4 v0 = *reinterpret_cast<const uint4*>(&x[(size_t)c0 * D + ci]);
    const uint4 v1 = *reinterpret_cast<const uint4*>(&x[(size_t)c1 * D + ci]);
    float f0[8], f1[8];
    f0[0] = blo(v0.x); f0[1] = bhi(v0.x); f0[2] = blo(v0.y); f0[3] = bhi(v0.y);
    f0[4] = blo(v0.z); f0[5] = bhi(v0.z); f0[6] = blo(v0.w); f0[7] = bhi(v0.w);
    f1[0] = blo(v1.x); f1[1] = bhi(v1.x); f1[2] = blo(v1.y); f1[3] = bhi(v1.y);
    f1[4] = blo(v1.z); f1[5] = bhi(v1.z); f1[6] = blo(v1.w); f1[7] = bhi(v1.w);
#pragma unroll
    for (int k = 0; k < 8; ++k) {
      a0[k] = fmaf(s0, f0[k], a0[k]);
      a1[k] = fmaf(s1, f1[k], a1[k]);
    }
    e0 += EPW;
    e1 += EPW;
  }

#pragma unroll
  for (int off = LPR; off < 64; off <<= 1) {
#pragma unroll
    for (int k = 0; k < 8; ++k) {
      a0[k] += __shfl_xor(a0[k], off, 64);
      a1[k] += __shfl_xor(a1[k], off, 64);
    }
  }

  // writers: lanes [0,LPR) -> n0 (a0), lanes [LPR,2LPR) -> n1 (a1)
  if (lane < 2 * LPR) {
    const bool g0 = lane < LPR;
    const int n = g0 ? n0 : n1;
    const int cw = (g0 ? lane : lane - LPR) * 8;
    const float* acc = g0 ? a0 : a1;
    const float s = nd[n];
    float4 b0 = *reinterpret_cast<const float4*>(&b[cw]);
    float4 b1 = *reinterpret_cast<const float4*>(&b[cw + 4]);
    float r[8];
    r[0] = fmaf(acc[0], s, b0.x); r[1] = fmaf(acc[1], s, b0.y);
    r[2] = fmaf(acc[2], s, b0.z); r[3] = fmaf(acc[3], s, b0.w);
    r[4] = fmaf(acc[4], s, b1.x); r[5] = fmaf(acc[5], s, b1.y);
    r[6] = fmaf(acc[6], s, b1.z); r[7] = fmaf(acc[7], s, b1.w);
    if (RELU) {
#pragma unroll
      for (int k = 0; k < 8; ++k) r[k] = fmaxf(r[k], 0.f);
    }
    if constexpr (OUTBF) {
      bhalf* out = (bhalf*)outp;
      uint4 p;
      p.x = pack2(r[0], r[1]);
      p.y = pack2(r[2], r[3]);
      p.z = pack2(r[4], r[5]);
      p.w = pack2(r[6], r[7]);
      *reinterpret_cast<uint4*>(&out[(size_t)n * D + cw]) = p;
    } else {
      float* out = (float*)outp;
      *reinterpret_cast<float4*>(&out[(size_t)n * D + cw]) =
          make_float4(r[0], r[1], r[2], r[3]);
      *reinterpret_cast<float4*>(&out[(size_t)n * D + cw + 4]) =
          make_float4(r[4], r[5], r[6], r[7]);
    }
  }
}

}  // namespace

extern "C" void kernel_launch(void* const* d_in, const int* in_sizes, int n_in,
                              void* d_out, int out_size, void* d_ws, size_t ws_size,
                              hipStream_t stream) {
  const float* h0  = (const float*)d_in[0];
  const int*   src = (const int*)d_in[1];
  const int*   dst = (const int*)d_in[2];
  const float* W0 = (const float*)d_in[3];
  const float* b0 = (const float*)d_in[4];
  const float* W1 = (const float*)d_in[5];
  const float* b1 = (const float*)d_in[6];
  const float* W2 = (const float*)d_in[7];
  const float* b2 = (const float*)d_in[8];
  const float* W3 = (const float*)d_in[9];
  const float* b3 = (const float*)d_in[10];
  float* out = (float*)d_out;

  // workspace layout (256B aligned)
  char* w = (char*)d_ws;
  size_t off = 0;
  auto take = [&](size_t bytes) {
    char* p = w + off;
    off = (off + bytes + 255) & ~size_t(255);
    return p;
  };
  int*   deg_out = (int*)take(NN * 4);   // adjacent: one memset covers both
  int*   deg_in  = (int*)take(NN * 4);
  float* nsrc    = (float*)take(NN * 4);
  float* ndst    = (float*)take(NN * 4);
  int*   rowptr  = (int*)take((NN + 1) * 4);
  int*   le      = (int*)take(NE * 4);
  int*   col     = (int*)take(NE * 4);
  int*   bsum    = (int*)take(NBLK * 4);
  int*   bpre    = (int*)take(NBLK * 4);
  bhalf* xbuf    = (bhalf*)take((size_t)NN * 128 * 2);  // bf16 GEMM outputs
  bhalf* hbuf    = (bhalf*)take((size_t)NN * 128 * 2);  // bf16 gather outputs
  bhalf* wt1     = (bhalf*)take(128 * 128 * 2);         // W1^T bf16
  bhalf* wt2     = (bhalf*)take(128 * 128 * 2);         // W2^T bf16
  bhalf* wt3     = (bhalf*)take(64 * 128 * 2);          // W3^T bf16
  (void)ws_size; (void)in_sizes; (void)n_in; (void)out_size;

  // zero both degree arrays (contiguous)
  hipMemsetAsync(deg_out, 0, (size_t)((char*)nsrc - (char*)deg_out), stream);

  const int EB = (NE + 255) / 256;

  // fused: degree atomics (blocks 0..255) + layer-0 GEMM x0 = h0@W0 (rest)
  gemm0_deg_kernel<<<DEG_BLOCKS + GEMM_TILES, 256, 0, stream>>>(
      h0, W0, xbuf, src, dst, deg_out, deg_in, le);
  // scan phase1 + norms + W->Wt bf16 convert (extra blocks, independent)
  scan1_norm_wcvt<<<NBLK + WCVT_BLOCKS, SCAN_BLK, 0, stream>>>(
      deg_out, deg_in, bsum, nsrc, ndst, W1, W2, W3, wt1, wt2, wt3);
  scan_phase2<<<1, 256, 0, stream>>>(bsum, bpre, rowptr);
  scan_phase3<<<NBLK, SCAN_BLK, 0, stream>>>(deg_in, bpre, rowptr);
  scatter_kernel<<<EB, 256, 0, stream>>>(src, dst, le, rowptr, col);

  const int GATHER_BLOCKS = (NN / 2 * 64 + 255) / 256;  // one wave / 2 nodes
  const int MFMA_BLOCKS = (NN / 16 + 3) / 4;            // 782

  // layer 0: x0 unscaled bf16 -> gather applies ns[col]; h1 bf16
  gather2_kernel<128, true, true, true><<<GATHER_BLOCKS, 256, 0, stream>>>(
      xbuf, rowptr, col, ndst, b0, nsrc, hbuf);
  // layer 1 (MFMA)
  gemm_mfma<128><<<MFMA_BLOCKS, 256, 0, stream>>>(hbuf, wt1, nsrc, xbuf);
  gather2_kernel<128, true, false, true><<<GATHER_BLOCKS, 256, 0, stream>>>(
      xbuf, rowptr, col, ndst, b1, nullptr, hbuf);
  // layer 2 (MFMA)
  gemm_mfma<128><<<MFMA_BLOCKS, 256, 0, stream>>>(hbuf, wt2, nsrc, xbuf);
  gather2_kernel<128, true, false, true><<<GATHER_BLOCKS, 256, 0, stream>>>(
      xbuf, rowptr, col, ndst, b2, nullptr, hbuf);
  // layer 3 (MFMA, DO=64): no relu, fp32 straight to d_out
  gemm_mfma<64><<<MFMA_BLOCKS, 256, 0, stream>>>(hbuf, wt3, nsrc, xbuf);
  gather2_kernel<64, false, false, false><<<GATHER_BLOCKS, 256, 0, stream>>>(
      xbuf, rowptr, col, ndst, b3, nullptr, out);
}

// Round 19
// 249.947 us; speedup vs baseline: 1.2739x; 1.0020x over previous
//
#include <hip/hip_runtime.h>

// GCN 4-layer forward on MI355X.
// Reference: h' = relu( norm_dst * segsum_{dst}( ((h*norm_src) @ W)[src] ) + b )
//
// Round 19: LDS-free MFMA gemm0 + full-parallel deg in one fused kernel.
// r14's fused0 (79us) ran the drain on 65k threads because the fp32 gemm0's
// 66.5KB LDS capped residency; MFMA gemm0 (h0 fp32->bf16 in-reg, W0t bf16
// precomputed) needs NO LDS, so the deg branch gets r16's full 2344-block
// parallelism (standalone 62us) and the ~5us of gemm0 fills bubbles.
// Also: all four W->Wt bf16 converts in one upfront kernel; scan2 folded
// into scan3 (each block re-derives its prefix from bsum).

namespace {

constexpr int NN = 50000;      // nodes
constexpr int NE = 600000;     // edges
constexpr int SCAN_BLK = 256;
constexpr int NBLK = (NN + SCAN_BLK - 1) / SCAN_BLK;  // 196
constexpr int EB = (NE + 255) / 256;                  // 2344 edge blocks
constexpr int MFMA0_BLOCKS = (NN / 16 + 3) / 4;       // 782 (4 tiles/block)
constexpr int WCVT_ELEMS = 16384 * 3 + 8192;          // W0,W1,W2 + W3
constexpr int WCVT_BLOCKS = WCVT_ELEMS / 256;         // 224

typedef unsigned short bhalf;
typedef __attribute__((ext_vector_type(8))) short short8v;   // 8 bf16
typedef __attribute__((ext_vector_type(4))) float f32x4;

__device__ inline float blo(unsigned int v) {  // low bf16 of a packed word
  return __uint_as_float(v << 16);
}
__device__ inline float bhi(unsigned int v) {  // high bf16 of a packed word
  return __uint_as_float(v & 0xFFFF0000u);
}
__device__ inline unsigned int f2b_bits(float f) {  // RNE bf16 in high 16 bits
  unsigned int b = __float_as_uint(f);
  return b + 0x7FFFu + ((b >> 16) & 1u);
}
__device__ inline unsigned int pack2(float lo, float hi) {
  return (f2b_bits(lo) >> 16) | (f2b_bits(hi) & 0xFFFF0000u);
}
__device__ inline bhalf f2b(float f) { return (bhalf)(f2b_bits(f) >> 16); }

// ---- upfront: Wt[j][k] = bf16(W[k][j]) for all four layer weights ----
__global__ __launch_bounds__(256) void wcvt_kernel(
    const float* __restrict__ W0, const float* __restrict__ W1,
    const float* __restrict__ W2, const float* __restrict__ W3,
    bhalf* __restrict__ wt0, bhalf* __restrict__ wt1,
    bhalf* __restrict__ wt2, bhalf* __restrict__ wt3) {
  int flat = blockIdx.x * 256 + threadIdx.x;
  if (flat < 16384) {
    int j = flat >> 7, k = flat & 127;
    wt0[flat] = f2b(W0[k * 128 + j]);
  } else if (flat < 32768) {
    int f = flat - 16384;
    int j = f >> 7, k = f & 127;
    wt1[f] = f2b(W1[k * 128 + j]);
  } else if (flat < 49152) {
    int f = flat - 32768;
    int j = f >> 7, k = f & 127;
    wt2[f] = f2b(W2[k * 128 + j]);
  } else {
    int f = flat - 49152;
    int j = f >> 7, k = f & 127;
    wt3[f] = f2b(W3[k * 64 + j]);
  }
}

// ---- fused: deg/le atomics at FULL parallelism + LDS-free MFMA gemm0 ----
// blocks [0,EB): 1 edge/thread (2 atomics + le store, exit).
// blocks [EB, EB+MFMA0_BLOCKS): x0 = bf16(h0) @ wt0, unscaled (ns into
// gather-0). A-frag converted fp32->bf16 in-reg; no LDS -> high residency.
__global__ __launch_bounds__(256, 4) void deg_gemm0_kernel(
    const int* __restrict__ src, const int* __restrict__ dst,
    int* __restrict__ dego, int* __restrict__ degi, int* __restrict__ le,
    const float* __restrict__ h, const bhalf* __restrict__ wt0,
    bhalf* __restrict__ x) {
  if (blockIdx.x < EB) {
    int e = blockIdx.x * 256 + threadIdx.x;
    if (e < NE) {
      atomicAdd(&dego[src[e]], 1);
      le[e] = atomicAdd(&degi[dst[e]], 1);
    }
    return;
  }
  const int lane = threadIdx.x & 63;
  const int wv = threadIdx.x >> 6;
  const int tile = (blockIdx.x - EB) * 4 + wv;
  if (tile >= NN / 16) return;
  const int row0 = tile * 16;
  const size_t arow = (size_t)(row0 + (lane & 15)) * 128;
  const int koff = (lane >> 4) * 8;
  const int bcol = lane & 15;

  f32x4 acc[8];
#pragma unroll
  for (int cf = 0; cf < 8; ++cf) acc[cf] = (f32x4){0.f, 0.f, 0.f, 0.f};

#pragma unroll
  for (int ks = 0; ks < 4; ++ks) {
    const int k0 = ks * 32 + koff;
    float4 ha = *reinterpret_cast<const float4*>(&h[arow + k0]);
    float4 hb = *reinterpret_cast<const float4*>(&h[arow + k0 + 4]);
    short8v av;
    av[0] = (short)f2b(ha.x); av[1] = (short)f2b(ha.y);
    av[2] = (short)f2b(ha.z); av[3] = (short)f2b(ha.w);
    av[4] = (short)f2b(hb.x); av[5] = (short)f2b(hb.y);
    av[6] = (short)f2b(hb.z); av[7] = (short)f2b(hb.w);
#pragma unroll
    for (int cf = 0; cf < 8; ++cf) {
      short8v bv = *reinterpret_cast<const short8v*>(
          &wt0[(size_t)(cf * 16 + bcol) * 128 + k0]);
      acc[cf] = __builtin_amdgcn_mfma_f32_16x16x32_bf16(av, bv, acc[cf], 0, 0, 0);
    }
  }

  const int crow = row0 + ((lane >> 4) << 2);
#pragma unroll
  for (int cf = 0; cf < 8; ++cf) {
#pragma unroll
    for (int r = 0; r < 4; ++r) {
      x[(size_t)(crow + r) * 128 + cf * 16 + bcol] = f2b(acc[cf][r]);
    }
  }
}

// --- scan phase 1 + norms ---
__global__ __launch_bounds__(SCAN_BLK) void scan1_norm(const int* __restrict__ dego,
                                                       const int* __restrict__ degi,
                                                       int* __restrict__ bsum,
                                                       float* __restrict__ ns,
                                                       float* __restrict__ nd) {
  __shared__ int ws[SCAN_BLK / 64];
  int i = blockIdx.x * SCAN_BLK + threadIdx.x;
  int v = 0;
  if (i < NN) {
    int din = degi[i];
    int dout = dego[i];
    v = din;
    int a = dout < 1 ? 1 : dout;
    int b = din < 1 ? 1 : din;
    ns[i] = 1.0f / sqrtf((float)a);
    nd[i] = 1.0f / sqrtf((float)b);
  }
#pragma unroll
  for (int off = 32; off; off >>= 1) v += __shfl_down(v, off, 64);
  int lane = threadIdx.x & 63, w = threadIdx.x >> 6;
  if (lane == 0) ws[w] = v;
  __syncthreads();
  if (threadIdx.x == 0) {
    int s = 0;
#pragma unroll
    for (int k = 0; k < SCAN_BLK / 64; ++k) s += ws[k];
    bsum[blockIdx.x] = s;
  }
}

// --- scan phases 2+3 merged: each block re-derives its prefix from bsum ---
__global__ __launch_bounds__(SCAN_BLK) void scan23(const int* __restrict__ deg,
                                                   const int* __restrict__ bsum,
                                                   int* __restrict__ rowptr) {
  __shared__ int sb[SCAN_BLK];   // bsum inclusive scan
  __shared__ int s[SCAN_BLK];    // local deg scan
  const int t = threadIdx.x;
  int vb = (t < NBLK) ? bsum[t] : 0;
  sb[t] = vb;
  __syncthreads();
  for (int off = 1; off < SCAN_BLK; off <<= 1) {
    int u = (t >= off) ? sb[t - off] : 0;
    __syncthreads();
    sb[t] += u;
    __syncthreads();
  }
  const int pre = (blockIdx.x == 0) ? 0 : sb[blockIdx.x - 1];
  if (blockIdx.x == NBLK - 1 && t == 0) rowptr[NN] = sb[NBLK - 1];  // == NE

  int i = blockIdx.x * SCAN_BLK + t;
  int v = (i < NN) ? deg[i] : 0;
  s[t] = v;
  __syncthreads();
  for (int off = 1; off < SCAN_BLK; off <<= 1) {
    int u = (t >= off) ? s[t - off] : 0;
    __syncthreads();
    s[t] += u;
    __syncthreads();
  }
  if (i < NN) rowptr[i] = pre + s[t] - v;
}

// atomic-free CSR fill using le slots recorded during counting
__global__ void scatter_kernel(const int* __restrict__ src, const int* __restrict__ dst,
                               const int* __restrict__ le, const int* __restrict__ rowptr,
                               int* __restrict__ col) {
  int e = blockIdx.x * blockDim.x + threadIdx.x;
  if (e < NE) col[rowptr[dst[e]] + le[e]] = src[e];
}

// ---- bf16 MFMA GEMM (r17, verified): one wave per 16-row tile ----
template <int DO>
__global__ __launch_bounds__(256, 2) void gemm_mfma(const bhalf* __restrict__ h,
                                                    const bhalf* __restrict__ wt,
                                                    const float* __restrict__ ns,
                                                    bhalf* __restrict__ x) {
  constexpr int CF = DO / 16;  // col fragments: 8 or 4
  const int lane = threadIdx.x & 63;
  const int wv = threadIdx.x >> 6;
  const int tile = blockIdx.x * 4 + wv;
  if (tile >= NN / 16) return;
  const int row0 = tile * 16;
  const size_t arow = (size_t)(row0 + (lane & 15)) * 128;
  const int koff = (lane >> 4) * 8;
  const int bcol = lane & 15;

  f32x4 acc[CF];
#pragma unroll
  for (int cf = 0; cf < CF; ++cf) acc[cf] = (f32x4){0.f, 0.f, 0.f, 0.f};

#pragma unroll
  for (int ks = 0; ks < 4; ++ks) {
    const int k0 = ks * 32 + koff;
    short8v av = *reinterpret_cast<const short8v*>(&h[arow + k0]);
#pragma unroll
    for (int cf = 0; cf < CF; ++cf) {
      short8v bv = *reinterpret_cast<const short8v*>(
          &wt[(size_t)(cf * 16 + bcol) * 128 + k0]);
      acc[cf] = __builtin_amdgcn_mfma_f32_16x16x32_bf16(av, bv, acc[cf], 0, 0, 0);
    }
  }

  const int crow = row0 + ((lane >> 4) << 2);
  float nsv[4];
#pragma unroll
  for (int r = 0; r < 4; ++r) nsv[r] = ns[crow + r];
#pragma unroll
  for (int cf = 0; cf < CF; ++cf) {
#pragma unroll
    for (int r = 0; r < 4; ++r) {
      x[(size_t)(crow + r) * DO + cf * 16 + bcol] = f2b(acc[cf][r] * nsv[r]);
    }
  }
}

// ---- Dual-node bf16 gather (r18, verified) ----
template <int D, bool RELU, bool NSRC, bool OUTBF>
__global__ __launch_bounds__(256) void gather2_kernel(const bhalf* __restrict__ x,
                                                      const int* __restrict__ rowptr,
                                                      const int* __restrict__ col,
                                                      const float* __restrict__ nd,
                                                      const float* __restrict__ b,
                                                      const float* __restrict__ nsv,
                                                      void* __restrict__ outp) {
  constexpr int LPR = D / 8;     // 16 (D=128) or 8 (D=64)
  constexpr int EPW = 64 / LPR;  // 4 or 8
  const int wid = (blockIdx.x * blockDim.x + threadIdx.x) >> 6;
  const int lane = threadIdx.x & 63;
  const int n0 = wid * 2;
  if (n0 >= NN) return;
  const int n1 = n0 + 1;
  const int sub = lane / LPR;
  const int ci = (lane % LPR) * 8;
  const int beg0 = rowptr[n0], end0 = rowptr[n0 + 1];
  const int beg1 = rowptr[n1], end1 = rowptr[n1 + 1];
  int e0 = beg0 + sub;
  int e1 = beg1 + sub;
  const int d0 = end0 - beg0, d1 = end1 - beg1;
  const int iters = ((d0 > d1 ? d0 : d1) + EPW - 1) / EPW;  // wave-uniform

  float a0[8], a1[8];
#pragma unroll
  for (int k = 0; k < 8; ++k) { a0[k] = 0.f; a1[k] = 0.f; }

#pragma unroll 2
  for (int it = 0; it < iters; ++it) {
    const bool p0 = e0 < end0;
    const bool p1 = e1 < end1;
    const int ee0 = p0 ? e0 : 0;      // clamped: col[0] is a valid address
    const int ee1 = p1 ? e1 : 0;
    const int c0 = col[ee0];
    const int c1 = col[ee1];
    const float s0 = p0 ? (NSRC ? nsv[c0] : 1.0f) : 0.0f;
    const float s1 = p1 ? (NSRC ? nsv[c1] : 1.0f) : 0.0f;
    const uint4 v0 = *reinterpret_cast<const uint4*>(&x[(size_t)c0 * D + ci]);
    const uint4 v1 = *reinterpret_cast<const uint4*>(&x[(size_t)c1 * D + ci]);
    float f0[8], f1[8];
    f0[0] = blo(v0.x); f0[1] = bhi(v0.x); f0[2] = blo(v0.y); f0[3] = bhi(v0.y);
    f0[4] = blo(v0.z); f0[5] = bhi(v0.z); f0[6] = blo(v0.w); f0[7] = bhi(v0.w);
    f1[0] = blo(v1.x); f1[1] = bhi(v1.x); f1[2] = blo(v1.y); f1[3] = bhi(v1.y);
    f1[4] = blo(v1.z); f1[5] = bhi(v1.z); f1[6] = blo(v1.w); f1[7] = bhi(v1.w);
#pragma unroll
    for (int k = 0; k < 8; ++k) {
      a0[k] = fmaf(s0, f0[k], a0[k]);
      a1[k] = fmaf(s1, f1[k], a1[k]);
    }
    e0 += EPW;
    e1 += EPW;
  }

#pragma unroll
  for (int off = LPR; off < 64; off <<= 1) {
#pragma unroll
    for (int k = 0; k < 8; ++k) {
      a0[k] += __shfl_xor(a0[k], off, 64);
      a1[k] += __shfl_xor(a1[k], off, 64);
    }
  }

  // writers: lanes [0,LPR) -> n0 (a0), lanes [LPR,2LPR) -> n1 (a1)
  if (lane < 2 * LPR) {
    const bool g0 = lane < LPR;
    const int n = g0 ? n0 : n1;
    const int cw = (g0 ? lane : lane - LPR) * 8;
    const float* acc = g0 ? a0 : a1;
    const float s = nd[n];
    float4 b0 = *reinterpret_cast<const float4*>(&b[cw]);
    float4 b1 = *reinterpret_cast<const float4*>(&b[cw + 4]);
    float r[8];
    r[0] = fmaf(acc[0], s, b0.x); r[1] = fmaf(acc[1], s, b0.y);
    r[2] = fmaf(acc[2], s, b0.z); r[3] = fmaf(acc[3], s, b0.w);
    r[4] = fmaf(acc[4], s, b1.x); r[5] = fmaf(acc[5], s, b1.y);
    r[6] = fmaf(acc[6], s, b1.z); r[7] = fmaf(acc[7], s, b1.w);
    if (RELU) {
#pragma unroll
      for (int k = 0; k < 8; ++k) r[k] = fmaxf(r[k], 0.f);
    }
    if constexpr (OUTBF) {
      bhalf* out = (bhalf*)outp;
      uint4 p;
      p.x = pack2(r[0], r[1]);
      p.y = pack2(r[2], r[3]);
      p.z = pack2(r[4], r[5]);
      p.w = pack2(r[6], r[7]);
      *reinterpret_cast<uint4*>(&out[(size_t)n * D + cw]) = p;
    } else {
      float* out = (float*)outp;
      *reinterpret_cast<float4*>(&out[(size_t)n * D + cw]) =
          make_float4(r[0], r[1], r[2], r[3]);
      *reinterpret_cast<float4*>(&out[(size_t)n * D + cw + 4]) =
          make_float4(r[4], r[5], r[6], r[7]);
    }
  }
}

}  // namespace

extern "C" void kernel_launch(void* const* d_in, const int* in_sizes, int n_in,
                              void* d_out, int out_size, void* d_ws, size_t ws_size,
                              hipStream_t stream) {
  const float* h0  = (const float*)d_in[0];
  const int*   src = (const int*)d_in[1];
  const int*   dst = (const int*)d_in[2];
  const float* W0 = (const float*)d_in[3];
  const float* b0 = (const float*)d_in[4];
  const float* W1 = (const float*)d_in[5];
  const float* b1 = (const float*)d_in[6];
  const float* W2 = (const float*)d_in[7];
  const float* b2 = (const float*)d_in[8];
  const float* W3 = (const float*)d_in[9];
  const float* b3 = (const float*)d_in[10];
  float* out = (float*)d_out;

  // workspace layout (256B aligned)
  char* w = (char*)d_ws;
  size_t off = 0;
  auto take = [&](size_t bytes) {
    char* p = w + off;
    off = (off + bytes + 255) & ~size_t(255);
    return p;
  };
  int*   deg_out = (int*)take(NN * 4);   // adjacent: one memset covers both
  int*   deg_in  = (int*)take(NN * 4);
  float* nsrc    = (float*)take(NN * 4);
  float* ndst    = (float*)take(NN * 4);
  int*   rowptr  = (int*)take((NN + 1) * 4);
  int*   le      = (int*)take(NE * 4);
  int*   col     = (int*)take(NE * 4);
  int*   bsum    = (int*)take(NBLK * 4);
  bhalf* xbuf    = (bhalf*)take((size_t)NN * 128 * 2);  // bf16 GEMM outputs
  bhalf* hbuf    = (bhalf*)take((size_t)NN * 128 * 2);  // bf16 gather outputs
  bhalf* wt0     = (bhalf*)take(128 * 128 * 2);         // W0^T bf16
  bhalf* wt1     = (bhalf*)take(128 * 128 * 2);         // W1^T bf16
  bhalf* wt2     = (bhalf*)take(128 * 128 * 2);         // W2^T bf16
  bhalf* wt3     = (bhalf*)take(64 * 128 * 2);          // W3^T bf16
  (void)ws_size; (void)in_sizes; (void)n_in; (void)out_size;

  // zero both degree arrays (contiguous)
  hipMemsetAsync(deg_out, 0, (size_t)((char*)nsrc - (char*)deg_out), stream);

  // 0) W -> Wt bf16 (all four), tiny
  wcvt_kernel<<<WCVT_BLOCKS, 256, 0, stream>>>(W0, W1, W2, W3, wt0, wt1, wt2, wt3);
  // 1) fused: full-parallel deg/le atomics + LDS-free MFMA gemm0
  deg_gemm0_kernel<<<EB + MFMA0_BLOCKS, 256, 0, stream>>>(
      src, dst, deg_out, deg_in, le, h0, wt0, xbuf);
  // 2) scan chain (2 launches)
  scan1_norm<<<NBLK, SCAN_BLK, 0, stream>>>(deg_out, deg_in, bsum, nsrc, ndst);
  scan23<<<NBLK, SCAN_BLK, 0, stream>>>(deg_in, bsum, rowptr);
  // 3) CSR fill
  scatter_kernel<<<EB, 256, 0, stream>>>(src, dst, le, rowptr, col);

  const int GATHER_BLOCKS = (NN / 2 * 64 + 255) / 256;  // one wave / 2 nodes
  const int MFMA_BLOCKS = (NN / 16 + 3) / 4;            // 782

  // layer 0: x0 unscaled bf16 -> gather applies ns[col]; h1 bf16
  gather2_kernel<128, true, true, true><<<GATHER_BLOCKS, 256, 0, stream>>>(
      xbuf, rowptr, col, ndst, b0, nsrc, hbuf);
  // layer 1 (MFMA)
  gemm_mfma<128><<<MFMA_BLOCKS, 256, 0, stream>>>(hbuf, wt1, nsrc, xbuf);
  gather2_kernel<128, true, false, true><<<GATHER_BLOCKS, 256, 0, stream>>>(
      xbuf, rowptr, col, ndst, b1, nullptr, hbuf);
  // layer 2 (MFMA)
  gemm_mfma<128><<<MFMA_BLOCKS, 256, 0, stream>>>(hbuf, wt2, nsrc, xbuf);
  gather2_kernel<128, true, false, true><<<GATHER_BLOCKS, 256, 0, stream>>>(
      xbuf, rowptr, col, ndst, b2, nullptr, hbuf);
  // layer 3 (MFMA, DO=64): no relu, fp32 straight to d_out
  gemm_mfma<64><<<MFMA_BLOCKS, 256, 0, stream>>>(hbuf, wt3, nsrc, xbuf);
  gather2_kernel<64, false, false, false><<<GATHER_BLOCKS, 256, 0, stream>>>(
      xbuf, rowptr, col, ndst, b3, nullptr, out);
}